// Round 7
// baseline (231.505 us; speedup 1.0000x reference)
//
#include <hip/hip_runtime.h>
#include <hip/hip_bf16.h>

// GCN forward: out = spmm(A, relu(spmm(A, x@W1)+b1) @ W2) + b2
// N=50000, F=512, H=128, C=40, E=800000
// Round 7: gemm1 restructured as B-stationary (whole W1t bf16 = 128KB in LDS,
// staged once), A streamed global->reg with 2-deep prefetch, ZERO barriers in
// the K-loop. Kills the per-K-step vmcnt(0)+barrier drain that kept gemm1
// latency-bound at 60us.

#define NFEAT 512
#define NHID  128
#define NCLS  40
#define BSH   8            // 256 dsts per bucket
#define ACHUNK 2048        // edges per bucketize block

typedef __attribute__((ext_vector_type(8))) short bf16x8;
typedef __attribute__((ext_vector_type(4))) short bf16x4;
typedef __attribute__((ext_vector_type(4))) float f32x4;

__device__ inline short f2bf(float f) {
  __hip_bfloat16 b = __float2bfloat16(f);
  return *reinterpret_cast<short*>(&b);
}

__device__ inline bf16x8 cvt8(float4 a, float4 b) {
  bf16x8 r;
  r[0] = f2bf(a.x); r[1] = f2bf(a.y); r[2] = f2bf(a.z); r[3] = f2bf(a.w);
  r[4] = f2bf(b.x); r[5] = f2bf(b.y); r[6] = f2bf(b.z); r[7] = f2bf(b.w);
  return r;
}

// ---------------- CSR build ----------------
__global__ __launch_bounds__(256) void hist_kernel(
    const int* __restrict__ edst, int* __restrict__ deg, int E) {
  int e = blockIdx.x * 256 + threadIdx.x;
  if (e < E) atomicAdd(&deg[edst[e]], 1);
}

__global__ __launch_bounds__(256) void scan_part(
    const int* __restrict__ deg, int* __restrict__ bsum, int n) {
  __shared__ int ws[4];
  int idx = blockIdx.x * 256 + threadIdx.x;
  int v = (idx < n) ? deg[idx] : 0;
#pragma unroll
  for (int o = 32; o > 0; o >>= 1) v += __shfl_down(v, o, 64);
  int lane = threadIdx.x & 63, w = threadIdx.x >> 6;
  if (lane == 0) ws[w] = v;
  __syncthreads();
  if (threadIdx.x == 0) bsum[blockIdx.x] = ws[0] + ws[1] + ws[2] + ws[3];
}

__global__ __launch_bounds__(1024) void scan_top(
    const int* __restrict__ bsum, int* __restrict__ boff,
    int* __restrict__ offs, int nchunk, int n) {
  __shared__ int part[1024];
  int tid = threadIdx.x;
  int v = (tid < nchunk) ? bsum[tid] : 0;
  part[tid] = v;
  __syncthreads();
  for (int o = 1; o < 1024; o <<= 1) {
    int t = (tid >= o) ? part[tid - o] : 0;
    __syncthreads();
    part[tid] += t;
    __syncthreads();
  }
  if (tid < nchunk) boff[tid] = part[tid] - v;
  if (tid == 0) offs[n] = part[nchunk - 1];
}

__global__ __launch_bounds__(256) void scan_apply(
    const int* __restrict__ deg, const int* __restrict__ boff,
    int* __restrict__ offs, int n) {
  __shared__ int part[256];
  int tid = threadIdx.x;
  int idx = blockIdx.x * 256 + tid;
  int v = (idx < n) ? deg[idx] : 0;
  part[tid] = v;
  __syncthreads();
  for (int o = 1; o < 256; o <<= 1) {
    int t = (tid >= o) ? part[tid - o] : 0;
    __syncthreads();
    part[tid] += t;
    __syncthreads();
  }
  if (idx < n) offs[idx] = boff[blockIdx.x] + part[tid] - v;
}

__global__ __launch_bounds__(256) void init_bcur(
    const int* __restrict__ offs, int* __restrict__ bcur, int nb) {
  int t = blockIdx.x * 256 + threadIdx.x;
  if (t < nb) bcur[t] = offs[t << BSH];
}

// ---- pass A: bucketize edges with block-local LDS counting sort ----
__global__ __launch_bounds__(256) void bucketize(
    const int* __restrict__ esrc, const int* __restrict__ edst,
    const float* __restrict__ ew, int* __restrict__ bcur,
    int* __restrict__ bsrc, float* __restrict__ bw, int* __restrict__ bdst,
    int E, int nb) {
  __shared__ int lh[256], lo[256], gbase[256];
  __shared__ int s_src[ACHUNK];
  __shared__ float s_w[ACHUNK];
  __shared__ int s_dst[ACHUNK];
  const int tid = threadIdx.x;
  const int base = blockIdx.x * ACHUNK;
  const int cnt = min(ACHUNK, E - base);

  for (int t = tid; t < nb; t += 256) lh[t] = 0;
  __syncthreads();

  int my_s[8], my_d[8], my_t[8];
  float my_w[8];
#pragma unroll
  for (int i = 0; i < 8; ++i) {
    int idx = base + i * 256 + tid;
    if (idx < E) {
      my_s[i] = esrc[idx];
      my_d[i] = edst[idx];
      my_w[i] = ew[idx];
      my_t[i] = atomicAdd(&lh[my_d[i] >> BSH], 1);
    }
  }
  __syncthreads();
  if (tid == 0) {
    int run = 0;
    for (int b = 0; b < nb; ++b) { lo[b] = run; run += lh[b]; }
  }
  __syncthreads();
  if (tid < nb && lh[tid] > 0) gbase[tid] = atomicAdd(&bcur[tid], lh[tid]);
  __syncthreads();
#pragma unroll
  for (int i = 0; i < 8; ++i) {
    int idx = base + i * 256 + tid;
    if (idx < E) {
      int p = lo[my_d[i] >> BSH] + my_t[i];
      s_src[p] = my_s[i];
      s_w[p] = my_w[i];
      s_dst[p] = my_d[i];
    }
  }
  __syncthreads();
  for (int j = tid; j < cnt; j += 256) {
    int d = s_dst[j];
    int b = d >> BSH;
    int g = gbase[b] + (j - lo[b]);
    bsrc[g] = s_src[j];
    bw[g] = s_w[j];
    bdst[g] = d;
  }
}

// ---- pass B: per-bucket final scatter, LDS cursors, packed int2 output ----
__global__ __launch_bounds__(256) void bucket_scatter(
    const int* __restrict__ offs, const int* __restrict__ bsrc,
    const float* __restrict__ bw, const int* __restrict__ bdst,
    int2* __restrict__ cwsrc, int n) {
  __shared__ int cur[1 << BSH];
  const int tid = threadIdx.x;
  const int d0 = blockIdx.x << BSH;
  const int nd = min(1 << BSH, n - d0);
  for (int t = tid; t < nd; t += 256) cur[t] = offs[d0 + t];
  __syncthreads();
  const int bstart = offs[d0];
  const int bend = offs[min(d0 + (1 << BSH), n)];
  for (int j = bstart + tid; j < bend; j += 256) {
    int d = bdst[j];
    int slot = atomicAdd(&cur[d - d0], 1);
    cwsrc[slot] = make_int2(bsrc[j], __float_as_int(bw[j]));
  }
}

// ---- W1 [512][128] f32 -> W1t [128][512] bf16 (transpose + convert) ----
__global__ __launch_bounds__(256) void w1t_kernel(
    const float* __restrict__ W1, __hip_bfloat16* __restrict__ W1t) {
  __shared__ float t[64][129];
  const int tid = threadIdx.x;
  const int k0 = blockIdx.x * 64;
#pragma unroll
  for (int i = 0; i < 8; ++i) {
    int f = i * 256 + tid;
    int r = f >> 5, c = (f & 31) << 2;
    float4 v = *(const float4*)&W1[(size_t)(k0 + r) * NHID + c];
    t[r][c] = v.x; t[r][c + 1] = v.y; t[r][c + 2] = v.z; t[r][c + 3] = v.w;
  }
  __syncthreads();
#pragma unroll
  for (int i = 0; i < 32; ++i) {
    int o = i * 256 + tid;
    int k = o & 63, n = o >> 6;
    W1t[(size_t)n * NFEAT + k0 + k] = __float2bfloat16(t[k][n]);
  }
}

// ---------- GEMM1 (MFMA): support[N,128] = bf16(x) @ bf16(W1), bf16 out ----------
// B-stationary: whole W1t (128x512 bf16 = 128KB) in LDS, swizzled, staged once.
// 4 waves x 32 rows, A direct global->reg with 2-deep prefetch, no K-loop barriers.
__global__ __launch_bounds__(256, 1) void gemm1_mfma(
    const float* __restrict__ x, const __hip_bfloat16* __restrict__ W1t,
    __hip_bfloat16* __restrict__ support, int nrows) {
  __shared__ __align__(16) char sB[128 * 512 * 2];   // 128 KB
  const int tid = threadIdx.x;
  const int lane = tid & 63;
  const int wv = tid >> 6;
  const int l15 = lane & 15, l4 = lane >> 4;
  const int row0 = blockIdx.x * 128 + wv * 32;

  // stage all of B, swizzled: byte = (col*1024 + k*2) ^ ((col&7)<<4)
#pragma unroll
  for (int i = 0; i < 32; ++i) {
    int idx = i * 256 + tid;            // 8192 bf16x8 chunks
    int col = idx >> 6;                 // 64 chunks per col row
    int kc = (idx & 63) << 3;           // k element offset
    bf16x8 v = *(const bf16x8*)&W1t[(size_t)col * NFEAT + kc];
    int byte = (col * 1024 + kc * 2) ^ ((col & 7) << 4);
    *(bf16x8*)(sB + byte) = v;
  }
  __syncthreads();

  f32x4 acc[2][8];
#pragma unroll
  for (int m = 0; m < 2; ++m)
#pragma unroll
    for (int n = 0; n < 8; ++n) acc[m][n] = (f32x4){0.f, 0.f, 0.f, 0.f};

  float4 pa[2][2][2];   // [buf][mfrag][half]
  auto LOADA = [&](int kt, int buf) {
#pragma unroll
    for (int m = 0; m < 2; ++m) {
      int row = row0 + m * 16 + l15;
      float4 z = make_float4(0.f, 0.f, 0.f, 0.f);
      if (row < nrows) {
        const float* p = &x[(size_t)row * NFEAT + kt * 32 + l4 * 8];
        pa[buf][m][0] = *(const float4*)p;
        pa[buf][m][1] = *(const float4*)(p + 4);
      } else {
        pa[buf][m][0] = z; pa[buf][m][1] = z;
      }
    }
  };

  LOADA(0, 0);
  LOADA(1, 1);
#pragma unroll
  for (int kt = 0; kt < 16; ++kt) {
    const int buf = kt & 1;
    bf16x8 af[2];
#pragma unroll
    for (int m = 0; m < 2; ++m) af[m] = cvt8(pa[buf][m][0], pa[buf][m][1]);
    if (kt + 2 < 16) LOADA(kt + 2, buf);
    bf16x8 bfr[8];
    const int k2 = (kt * 32 + l4 * 8) * 2;
#pragma unroll
    for (int n = 0; n < 8; ++n) {
      int col = n * 16 + l15;
      bfr[n] = *(const bf16x8*)(sB + ((col * 1024 + k2) ^ ((col & 7) << 4)));
    }
#pragma unroll
    for (int m = 0; m < 2; ++m)
#pragma unroll
      for (int n = 0; n < 8; ++n)
        acc[m][n] = __builtin_amdgcn_mfma_f32_16x16x32_bf16(af[m], bfr[n], acc[m][n], 0, 0, 0);
  }

  // C/D layout: col = lane&15, row = (lane>>4)*4 + reg
#pragma unroll
  for (int m = 0; m < 2; ++m) {
#pragma unroll
    for (int r = 0; r < 4; ++r) {
      int grow = row0 + m * 16 + l4 * 4 + r;
      if (grow < nrows) {
#pragma unroll
        for (int n = 0; n < 8; ++n) {
          support[(size_t)grow * NHID + n * 16 + l15] = __float2bfloat16(acc[m][n][r]);
        }
      }
    }
  }
}

__device__ inline void bf2unpack(unsigned int u, float& lo, float& hi) {
  union { unsigned int ui; float f; } a, b;
  a.ui = (u & 0xffffu) << 16;
  b.ui = u & 0xffff0000u;
  lo = a.f; hi = b.f;
}

// ------- SpMM1 gather: h[n,f] = relu(b1[f] + sum_e w_e * support[src_e, f]) -------
__global__ __launch_bounds__(256) void spmm1_gather(
    const int* __restrict__ offs, const int2* __restrict__ cwsrc,
    const __hip_bfloat16* __restrict__ support,
    const float* __restrict__ b1, float* __restrict__ h, int n) {
  int node = blockIdx.x * 4 + (threadIdx.x >> 6);
  int f2 = threadIdx.x & 63;
  if (node >= n) return;
  int beg = offs[node], end = offs[node + 1];
  float a0 = 0.f, a1 = 0.f;
  const unsigned int* sp = (const unsigned int*)support;
  int i = beg;
  for (; i + 3 < end; i += 4) {
    int2 e0 = cwsrc[i], e1 = cwsrc[i + 1], e2 = cwsrc[i + 2], e3 = cwsrc[i + 3];
    unsigned int u0 = sp[(size_t)e0.x * 64 + f2];
    unsigned int u1 = sp[(size_t)e1.x * 64 + f2];
    unsigned int u2 = sp[(size_t)e2.x * 64 + f2];
    unsigned int u3 = sp[(size_t)e3.x * 64 + f2];
    float lo, hi;
    float w0 = __int_as_float(e0.y), w1 = __int_as_float(e1.y);
    float w2 = __int_as_float(e2.y), w3 = __int_as_float(e3.y);
    bf2unpack(u0, lo, hi); a0 += w0 * lo; a1 += w0 * hi;
    bf2unpack(u1, lo, hi); a0 += w1 * lo; a1 += w1 * hi;
    bf2unpack(u2, lo, hi); a0 += w2 * lo; a1 += w2 * hi;
    bf2unpack(u3, lo, hi); a0 += w3 * lo; a1 += w3 * hi;
  }
  for (; i < end; ++i) {
    int2 e = cwsrc[i];
    float w = __int_as_float(e.y);
    unsigned int u = sp[(size_t)e.x * 64 + f2];
    float lo, hi;
    bf2unpack(u, lo, hi);
    a0 += w * lo; a1 += w * hi;
  }
  float2 o;
  o.x = fmaxf(a0 + b1[f2 * 2], 0.f);
  o.y = fmaxf(a1 + b1[f2 * 2 + 1], 0.f);
  *(float2*)&h[(size_t)node * NHID + f2 * 2] = o;
}

// ------- GEMM2: s2[N,40] = h @ W2[128,40] -> bf16 out ------
__global__ __launch_bounds__(256) void gemm2_kernel(
    const float* __restrict__ h, const float* __restrict__ W2,
    __hip_bfloat16* __restrict__ s2, int nrows) {
  __shared__ float sh[32][128];
  __shared__ float swt[128][40];
  const int tid = threadIdx.x;
  for (int i = tid; i < 128 * 40; i += 256) swt[i / 40][i % 40] = W2[i];
  __syncthreads();
  const int row0 = blockIdx.x * 32;
#pragma unroll
  for (int i = 0; i < 4; ++i) {
    int f = tid + 256 * i;
    int r = f >> 5, c = (f & 31) << 2;
    int gr = row0 + r;
    float4 v = make_float4(0.f, 0.f, 0.f, 0.f);
    if (gr < nrows) v = *(const float4*)&h[(size_t)gr * NHID + c];
    sh[r][c] = v.x; sh[r][c + 1] = v.y; sh[r][c + 2] = v.z; sh[r][c + 3] = v.w;
  }
  __syncthreads();
#pragma unroll
  for (int j = 0; j < 5; ++j) {
    int o = tid + 256 * j;
    int r = o / 40, c = o % 40;
    float acc = 0.f;
#pragma unroll 8
    for (int k = 0; k < 128; ++k) acc += sh[r][k] * swt[k][c];
    int gr = row0 + r;
    if (gr < nrows) s2[(size_t)gr * NCLS + c] = __float2bfloat16(acc);
  }
}

// ------- SpMM2 gather: out[n,c] = b2[c] + sum_e w_e * s2[src_e, c] -------
__global__ __launch_bounds__(256) void spmm2_gather(
    const int* __restrict__ offs, const int2* __restrict__ cwsrc,
    const __hip_bfloat16* __restrict__ s2,
    const float* __restrict__ b2, float* __restrict__ out, int n) {
  int node = blockIdx.x * 8 + (threadIdx.x >> 5);
  int f2 = threadIdx.x & 31;
  if (node >= n || f2 >= 20) return;
  int beg = offs[node], end = offs[node + 1];
  float a0 = 0.f, a1 = 0.f;
  const unsigned int* sp = (const unsigned int*)s2;
  int i = beg;
  for (; i + 3 < end; i += 4) {
    int2 e0 = cwsrc[i], e1 = cwsrc[i + 1], e2 = cwsrc[i + 2], e3 = cwsrc[i + 3];
    unsigned int u0 = sp[(size_t)e0.x * 20 + f2];
    unsigned int u1 = sp[(size_t)e1.x * 20 + f2];
    unsigned int u2 = sp[(size_t)e2.x * 20 + f2];
    unsigned int u3 = sp[(size_t)e3.x * 20 + f2];
    float lo, hi;
    float w0 = __int_as_float(e0.y), w1 = __int_as_float(e1.y);
    float w2 = __int_as_float(e2.y), w3 = __int_as_float(e3.y);
    bf2unpack(u0, lo, hi); a0 += w0 * lo; a1 += w0 * hi;
    bf2unpack(u1, lo, hi); a0 += w1 * lo; a1 += w1 * hi;
    bf2unpack(u2, lo, hi); a0 += w2 * lo; a1 += w2 * hi;
    bf2unpack(u3, lo, hi); a0 += w3 * lo; a1 += w3 * hi;
  }
  for (; i < end; ++i) {
    int2 e = cwsrc[i];
    float w = __int_as_float(e.y);
    unsigned int u = sp[(size_t)e.x * 20 + f2];
    float lo, hi;
    bf2unpack(u, lo, hi);
    a0 += w * lo; a1 += w * hi;
  }
  float2 o;
  o.x = a0 + b2[f2 * 2];
  o.y = a1 + b2[f2 * 2 + 1];
  *(float2*)&out[(size_t)node * NCLS + f2 * 2] = o;
}

extern "C" void kernel_launch(void* const* d_in, const int* in_sizes, int n_in,
                              void* d_out, int out_size, void* d_ws, size_t ws_size,
                              hipStream_t stream) {
  const float* x   = (const float*)d_in[0];
  const float* W1  = (const float*)d_in[1];
  const float* b1  = (const float*)d_in[2];
  const float* W2  = (const float*)d_in[3];
  const float* b2  = (const float*)d_in[4];
  const int* esrc  = (const int*)d_in[5];
  const int* edst  = (const int*)d_in[6];
  const float* ew  = (const float*)d_in[7];
  float* out = (float*)d_out;

  const int N = in_sizes[0] / NFEAT;        // 50000
  const int E = in_sizes[5];                // 800000
  const int NCHUNK = (N + 255) / 256;       // 196
  const int NB = (N + (1 << BSH) - 1) >> BSH;  // 196 buckets

  char* ws = (char*)d_ws;
  size_t off = 0;
  auto alloc = [&](size_t bytes) {
    void* p = ws + off;
    off += (bytes + 255) & ~(size_t)255;
    return p;
  };
  int2*  cwsrc   = (int2*)alloc((size_t)E * 8);
  int*   offs    = (int*)alloc((size_t)(N + 1) * 4);
  int*   deg     = (int*)alloc((size_t)N * 4);
  int*   bsum    = (int*)alloc((size_t)NCHUNK * 4);
  int*   boff    = (int*)alloc((size_t)NCHUNK * 4);
  int*   bcur    = (int*)alloc((size_t)NB * 4);
  __hip_bfloat16* W1t     = (__hip_bfloat16*)alloc((size_t)NHID * NFEAT * 2);
  __hip_bfloat16* support = (__hip_bfloat16*)alloc((size_t)N * NHID * 2);
  float* h       = (float*)alloc((size_t)N * NHID * 4);
  __hip_bfloat16* s2 = (__hip_bfloat16*)alloc((size_t)N * NCLS * 2);
  // bucket arrays alias h (dead until spmm1, which runs after bucket_scatter)
  int*   bsrc = (int*)h;
  float* bw   = (float*)(h + E);
  int*   bdst = (int*)(h + 2 * (size_t)E);

  // ---- CSR build ----
  hipMemsetAsync(deg, 0, (size_t)N * 4, stream);
  hist_kernel<<<(E + 255) / 256, 256, 0, stream>>>(edst, deg, E);
  scan_part<<<NCHUNK, 256, 0, stream>>>(deg, bsum, N);
  scan_top<<<1, 1024, 0, stream>>>(bsum, boff, offs, NCHUNK, N);
  scan_apply<<<NCHUNK, 256, 0, stream>>>(deg, boff, offs, N);
  init_bcur<<<(NB + 255) / 256, 256, 0, stream>>>(offs, bcur, NB);
  bucketize<<<(E + ACHUNK - 1) / ACHUNK, 256, 0, stream>>>(
      esrc, edst, ew, bcur, bsrc, bw, bdst, E, NB);
  bucket_scatter<<<NB, 256, 0, stream>>>(offs, bsrc, bw, bdst, cwsrc, N);

  // ---- layer 1 ----
  w1t_kernel<<<NFEAT / 64, 256, 0, stream>>>(W1, W1t);
  gemm1_mfma<<<(N + 127) / 128, 256, 0, stream>>>(x, W1t, support, N);
  spmm1_gather<<<(N + 3) / 4, 256, 0, stream>>>(offs, cwsrc, support, b1, h, N);

  // ---- layer 2 ----
  gemm2_kernel<<<(N + 31) / 32, 256, 0, stream>>>(h, W2, s2, N);
  spmm2_gather<<<(N + 7) / 8, 256, 0, stream>>>(offs, cwsrc, s2, b2, out, N);
}